// Round 9
// baseline (188.559 us; speedup 1.0000x reference)
//
#include <hip/hip_runtime.h>

// Concordance index, status-partitioned formulation (validated R4-R8, absmax 0.0).
// answer = (CC_full - K) / (TP_full - K), K = #(status==1), le == !ge.
//   region (1,1): cc = (ge==geh), tp = 1      -> tp analytic K^2
//   region (0,1) == (1,0) transposed          -> compute once, double
//   region (0,0): contributes nothing         -> skipped
// EQ = slots - NE over padded A tiles (every sentinel-involved pair gives
// ne==1, absorbed by the slots constant). CC_full = EQ + 2*BC;
// TP_full = K^2 + 2*BG. Sentinels: j-pad (+inf,-inf); A i-pad (-inf,+inf)
// (ne=1 always); B i-pad (-inf,-inf) (ge=0 always -> 0 to BG/BC).
// R9: WAVE-AUTONOMOUS tiles. R8 showed the kernel is occupancy/latency-bound
// (~5M wave-insts total but 23% occ, 21% VALUBusy): block-level barriers +
// 1-tile-per-block serialized everything. Now each WAVE owns one 128x128
// tile, stages its own private 1KB LDS j-slice (intra-wave dependency ->
// s_waitcnt only, NO __syncthreads in main loop), 8192 wave-tiles on
// 8 waves/SIMD. Atomics diffused over 64 slots; parallel last-block reduce.

#define BLOCK 256
#define TJ 128
#define IT 2
#define TI 128                   // 2 i-vals x 64 lanes
#define GRID_PAIRS 2048
#define NSLOT 64

// ws: [0] u32 cnts[2] (K,M); [8] u32 done; [16] ull acc[NSLOT*3];
//     [2048] float2 p1[stride], p0[stride]

__global__ __launch_bounds__(256) void compact_kernel(
    const float* __restrict__ y, const float* __restrict__ yh,
    const int* __restrict__ status, int n,
    unsigned* __restrict__ cnts,
    float2* __restrict__ p1, float2* __restrict__ p0)
{
    int i = blockIdx.x * 256 + threadIdx.x;
    int lane = threadIdx.x & 63;
    bool act = i < n;
    float yv  = act ? y[i]  : 0.0f;
    float yhv = act ? yh[i] : 0.0f;
    bool st = act && (status[i] == 1);
    unsigned long long m1 = __ballot(st);
    unsigned long long m0 = __ballot(act && !st);
    unsigned long long lt = (1ull << lane) - 1ull;
    unsigned b1 = 0, b0 = 0;
    if (lane == 0) {
        b1 = atomicAdd(&cnts[0], (unsigned)__popcll(m1));
        b0 = atomicAdd(&cnts[1], (unsigned)__popcll(m0));
    }
    b1 = __shfl(b1, 0, 64);
    b0 = __shfl(b0, 0, 64);
    if (st) {
        p1[b1 + (unsigned)__popcll(m1 & lt)] = make_float2(yv, yhv);
    } else if (act) {
        p0[b0 + (unsigned)__popcll(m0 & lt)] = make_float2(yv, yhv);
    }
}

__global__ __launch_bounds__(BLOCK) void pairs_kernel(
    const unsigned* __restrict__ cnts,
    const float2* __restrict__ p1, const float2* __restrict__ p0,
    unsigned long long* __restrict__ acc, unsigned* __restrict__ done,
    float* __restrict__ out)
{
    __shared__ float2 s_j[4][TJ];      // private 1KB slice per wave
    __shared__ int s_flag;
    __shared__ unsigned long long s_fin[3];

    const int tid = threadIdx.x;
    const int wave = tid >> 6, lane = tid & 63;
    const unsigned K = cnts[0], M = cnts[1];
    const int ntJ  = (int)((K + TJ - 1) / TJ);
    const int ntIA = (int)((K + TI - 1) / TI);
    const int ntIB = (int)((M + TI - 1) / TI);
    const int ntA  = ntIA * ntJ;
    const int ntot = ntA + ntIB * ntJ;
    const float PINF = __int_as_float(0x7f800000);
    const float NINF = __int_as_float(0xff800000);
    const float NANF = __int_as_float(0x7fc00000);

    const int gw = blockIdx.x * 4 + wave;
    const int nw = gridDim.x * 4;

    unsigned aNE = 0, aBG = 0, aBC = 0;

    for (int t = gw; t < ntot; t += nw) {
        bool isA = t < ntA;
        int tt = isA ? t : t - ntA;
        int ti = tt / ntJ;
        int tj = tt - ti * ntJ;

        // stage this wave's j slice (same-wave use -> waitcnt only, no barrier)
        {
            int j0 = tj * TJ + lane;                    // < K+127 < stride: safe
            float2 a = p1[j0];
            float2 b = p1[j0 + 64];
            if ((unsigned)j0        >= K) a = make_float2(PINF, NINF);
            if ((unsigned)(j0 + 64) >= K) b = make_float2(PINF, NINF);
            s_j[wave][lane]      = a;
            s_j[wave][lane + 64] = b;
        }

        const float2* pi = isA ? p1 : p0;
        unsigned ilim = isA ? K : M;
        int ib = ti * TI + lane;                        // < ilim+127 < stride: safe
        float2 sent = isA ? make_float2(NINF, PINF)     // A i-pad: ne=1 always
                          : make_float2(NINF, NINF);    // B i-pad: ge=0 always
        float2 v0 = pi[ib];       if ((unsigned)ib        >= ilim) v0 = sent;
        float2 v1 = pi[ib + 64];  if ((unsigned)(ib + 64) >= ilim) v1 = sent;

        if (isA) {
            unsigned n0 = 0, n1 = 0;
#pragma unroll 8
            for (int jj = 0; jj < TJ; ++jj) {
                float2 p = s_j[wave][jj];
                n0 += (unsigned)((v0.x >= p.x) != (v0.y >= p.y));
                n1 += (unsigned)((v1.x >= p.x) != (v1.y >= p.y));
            }
            aNE += n0 + n1;
        } else {
            unsigned g0 = 0, g1 = 0, c0 = 0, c1 = 0;
#pragma unroll 8
            for (int jj = 0; jj < TJ; ++jj) {
                float2 p = s_j[wave][jj];
                g0 += (unsigned)(v0.x >= p.x);
                float t0 = (v0.x >= p.x) ? v0.y : NANF;   // AND via select-NaN
                c0 += (unsigned)(t0 >= p.y);
                g1 += (unsigned)(v1.x >= p.x);
                float t1 = (v1.x >= p.x) ? v1.y : NANF;
                c1 += (unsigned)(t1 >= p.y);
            }
            aBG += g0 + g1; aBC += c0 + c1;
        }
        // no barrier: next iteration overwrites only this wave's LDS slice
    }

    // wave-level reduce, diffused atomic merge (64 slots x 3 counters)
#pragma unroll
    for (int off = 32; off > 0; off >>= 1) {
        aNE += __shfl_down(aNE, off, 64);
        aBC += __shfl_down(aBC, off, 64);
        aBG += __shfl_down(aBG, off, 64);
    }
    if (lane == 0) {
        int slot = (gw & (NSLOT - 1)) * 3;
        if (aNE) atomicAdd(&acc[slot + 0], (unsigned long long)aNE);
        if (aBC) atomicAdd(&acc[slot + 1], (unsigned long long)aBC);
        if (aBG) atomicAdd(&acc[slot + 2], (unsigned long long)aBG);
        __threadfence();
    }
    __syncthreads();
    if (tid == 0) {
        s_flag = (atomicAdd(done, 1u) == (unsigned)(gridDim.x - 1));
    }
    __syncthreads();

    if (s_flag) {                       // last block: parallel finalize
        __threadfence();
        if (wave < 3) {
            unsigned long long v = acc[lane * 3 + wave];
#pragma unroll
            for (int off = 32; off > 0; off >>= 1)
                v += __shfl_down(v, off, 64);
            if (lane == 0) s_fin[wave] = v;
        }
        __syncthreads();
        if (tid == 0) {
            unsigned long long NE = s_fin[0], BC = s_fin[1], BG = s_fin[2];
            unsigned long long Kl = K;
            unsigned long long slots = (unsigned long long)(ntIA * TI) *
                                       (unsigned long long)(ntJ * TJ);
            unsigned long long EQ = slots - NE;
            unsigned long long CC = EQ + 2ull * BC;
            unsigned long long TP = Kl * Kl + 2ull * BG;
            long long cn = (long long)CC - (long long)Kl;
            long long tn = (long long)TP - (long long)Kl;
            out[0] = (float)cn / (float)tn;
        }
    }
}

extern "C" void kernel_launch(void* const* d_in, const int* in_sizes, int n_in,
                              void* d_out, int out_size, void* d_ws, size_t ws_size,
                              hipStream_t stream) {
    const float* y      = (const float*)d_in[0];
    const float* y_hat  = (const float*)d_in[1];
    const int*   status = (const int*)d_in[2];
    float* out = (float*)d_out;
    int n = in_sizes[0];
    int stride = n + 1024;

    char* base = (char*)d_ws;
    unsigned* cnts = (unsigned*)base;
    unsigned* done = (unsigned*)(base + 8);
    unsigned long long* acc = (unsigned long long*)(base + 16);
    float2* p1 = (float2*)(base + 2048);
    float2* p0 = p1 + stride;

    hipMemsetAsync(base, 0, 2048, stream);

    hipLaunchKernelGGL(compact_kernel, dim3((n + 255) / 256), dim3(256), 0, stream,
                       y, y_hat, status, n, cnts, p1, p0);

    hipLaunchKernelGGL(pairs_kernel, dim3(GRID_PAIRS), dim3(BLOCK), 0, stream,
                       cnts, p1, p0, acc, done, out);
}